// Round 3
// baseline (1436.340 us; speedup 1.0000x reference)
//
#include <hip/hip_runtime.h>
#include <hip/hip_bf16.h>

// Problem constants (from reference setup_inputs)
#define NNODES 65536
#define KTOT   32768      // N_SRC
#define MTOT   8192       // N_DST
#define DIM    128        // SRC_DIM == DST_DIM
#define SPLIT  8
#define KC     (KTOT / SPLIT)   // 4096 per split
#define BK     64
#define NSTEP  (KC / BK)        // 64
#define BM     128

typedef float f32x16 __attribute__((ext_vector_type(16)));
typedef float f32x4  __attribute__((ext_vector_type(4)));
typedef short s16x8  __attribute__((ext_vector_type(8)));

// fp32 -> bf16 bits, round-to-nearest-even
__device__ __forceinline__ short f2bf(float f) {
  union { float f; unsigned u; } v; v.f = f;
  unsigned r = v.u + 0x7FFFu + ((v.u >> 16) & 1u);
  return (short)(r >> 16);
}

#define GLOAD_LDS16(gp, lp)                                                   \
  __builtin_amdgcn_global_load_lds(                                           \
      (const __attribute__((address_space(1))) void*)(gp),                    \
      (__attribute__((address_space(3))) void*)(lp), 16, 0, 0)

// ---------------------------------------------------------------------------
// Kernel 1: gather src rows, cast fp32->bf16, store TRANSPOSED wsB[n][k]
// (n-major, row length KTOT). Grid: 512 blocks x 256 thr; each block owns a
// 64-wide k-tile. Thread t: n4 = t>>3 (4 cols), k8 = t&7 (8 k's).
// ---------------------------------------------------------------------------
__global__ __launch_bounds__(256) void prep_kernel(
    const float* __restrict__ feat, const int* __restrict__ s2src,
    short* __restrict__ wsB) {
  const int t  = threadIdx.x;
  const int k0 = blockIdx.x * 64;
  const int n4 = t >> 3;
  const int k8 = t & 7;
  s16x8 ob[4];
  #pragma unroll
  for (int i = 0; i < 8; ++i) {
    const int k   = k0 + k8 * 8 + i;
    const int row = s2src[k];
    const f32x4 v = *(const f32x4*)(feat + (size_t)row * DIM + n4 * 4);
    #pragma unroll
    for (int c = 0; c < 4; ++c) ob[c][i] = f2bf(v[c]);
  }
  #pragma unroll
  for (int c = 0; c < 4; ++c) {
    const int n = n4 * 4 + c;
    *(s16x8*)(wsB + (size_t)n * KTOT + k0 + k8 * 8) = ob[c];
  }
}

// ---------------------------------------------------------------------------
// Kernel 2: split-K MFMA GEMM.  partial[split] = dif[:, kchunk] @ srcT
// Block = 256 thr (4 waves), tile = 128 rows x 128 cols, BK=64.
// split = blockIdx & 7 so that split == XCD (hardware round-robins
// blockIdx % 8): each XCD's 4 MiB L2 holds exactly its own 1 MiB B chunk.
// A (fp32) -> registers in 32x32x16 fragment order, converted to bf16.
// B (bf16, transposed ws) -> LDS [n][k] via global_load_lds, XOR-16 swizzle
// applied on the GLOBAL source address (LDS dest stays linear), same XOR on
// the ds_read side (both-sides-or-neither, rule #21).
// ---------------------------------------------------------------------------
__global__ __launch_bounds__(256, 2) void gemm_kernel(
    const float* __restrict__ A,   // dif_mat [MTOT][KTOT]
    const short* __restrict__ B,   // wsB [DIM][KTOT] bf16 bits
    float* __restrict__ P) {       // partials [SPLIT][MTOT][DIM]
  __shared__ short Blds[2][BM * BK];   // 2 x 16 KiB

  const int tid   = threadIdx.x;
  const int lane  = tid & 63;
  const int wid   = tid >> 6;
  const int split = blockIdx.x & 7;    // == XCD id (hw round-robin)
  const int tile  = blockIdx.x >> 3;
  const int kbase = split * KC;
  const int m0    = tile * BM + wid * 32;
  const int l31   = lane & 31;
  const int lhi   = lane >> 5;

  const float* Ap = A + (size_t)(m0 + l31) * KTOT + kbase + lhi * 8;

  f32x16 acc[4];
  #pragma unroll
  for (int c = 0; c < 4; ++c)
    #pragma unroll
    for (int r = 0; r < 16; ++r) acc[c][r] = 0.f;

  auto stage = [&](int buf, int kk) {
    #pragma unroll
    for (int it = 0; it < 4; ++it) {
      const int o  = wid * 4096 + it * 1024 + lane * 16;  // byte off in tile
      const int n  = o >> 7;                              // 128 B per n-row
      const int kb = (o & 127) ^ ((n & 7) << 4);          // inverse swizzle
      const char* src = (const char*)B + (size_t)n * (KTOT * 2)
                        + (size_t)(kbase + kk * BK) * 2 + kb;
      GLOAD_LDS16(src, (char*)&Blds[buf][0] + wid * 4096 + it * 1024);
    }
  };

  stage(0, 0);
  __syncthreads();

  #pragma unroll 2
  for (int kk = 0; kk < NSTEP; ++kk) {
    const int cur = kk & 1;
    if (kk + 1 < NSTEP) stage(cur ^ 1, kk + 1);

    // A: 4 ksub x 8 fp32 per lane, fragment order (row=l31, k=lhi*8+j)
    const float* ap = Ap + kk * BK;
    f32x4 av[4][2];
    #pragma unroll
    for (int ks = 0; ks < 4; ++ks) {
      av[ks][0] = *(const f32x4*)(ap + ks * 16);
      av[ks][1] = *(const f32x4*)(ap + ks * 16 + 4);
    }
    s16x8 af[4];
    #pragma unroll
    for (int ks = 0; ks < 4; ++ks)
      #pragma unroll
      for (int j = 0; j < 8; ++j)
        af[ks][j] = f2bf(av[ks][j >> 2][j & 3]);

    const char* bb = (const char*)&Blds[cur][0];
    #pragma unroll
    for (int c = 0; c < 4; ++c) {
      const int n = c * 32 + l31;
      const int rowbase = n * 128;
      const int x = (n & 7) << 4;
      #pragma unroll
      for (int ks = 0; ks < 4; ++ks) {
        const int kb = (ks * 32 + lhi * 16) ^ x;
        const s16x8 bf = *(const s16x8*)(bb + rowbase + kb);
        acc[c] =
            __builtin_amdgcn_mfma_f32_32x32x16_bf16(af[ks], bf, acc[c], 0, 0, 0);
      }
    }
    __syncthreads();
  }

  // C/D layout (m74/m101): col = lane&31, row = (r&3) + 8*(r>>2) + 4*(lane>>5)
  float* out = P + (size_t)split * (MTOT * DIM);
  #pragma unroll
  for (int c = 0; c < 4; ++c) {
    const int col = c * 32 + l31;
    #pragma unroll
    for (int r = 0; r < 16; ++r) {
      const int rowo = (r & 3) + 8 * (r >> 2) + 4 * lhi;
      out[(size_t)(m0 + rowo) * DIM + col] = acc[c][r];
    }
  }
}

// ---------------------------------------------------------------------------
// Kernel 3: reduce partials + gather dst + (concat @ w) + relu.
// Block = 256 thr handles 16 dst rows. LDS concat tile [k=256][r=16] padded
// to 20 floats/row (bounded store conflict, aligned broadcast reads).
// ---------------------------------------------------------------------------
__global__ __launch_bounds__(256) void finish_kernel(
    const float* __restrict__ feat, const int* __restrict__ s2dst,
    const float* __restrict__ P, const float* __restrict__ w,
    float* __restrict__ out) {
  __shared__ float lds[256][20];
  const int t  = threadIdx.x;
  const int i0 = blockIdx.x * 16;

  #pragma unroll 4
  for (int r = 0; r < 16; ++r) {
    const int i = i0 + r;
    float v;
    if (t < 128) {            // aggregated part: sum 8 partials
      v = 0.f;
      #pragma unroll
      for (int s = 0; s < SPLIT; ++s)
        v += P[(size_t)s * (MTOT * DIM) + (size_t)i * DIM + t];
    } else {                  // dst-feature part
      v = feat[(size_t)s2dst[i] * DIM + (t - 128)];
    }
    lds[t][r] = v;            // lds[k][r]
  }
  __syncthreads();

  const int j  = t & 127;
  const int rg = t >> 7;      // 0 or 1 -> rows rg*8 .. rg*8+7
  float acc[8];
  #pragma unroll
  for (int r8 = 0; r8 < 8; ++r8) acc[r8] = 0.f;

  #pragma unroll 4
  for (int k = 0; k < 256; ++k) {
    const float wv = w[k * DIM + j];
    const float* lr = &lds[k][rg * 8];   // 16B-aligned, broadcast reads
    #pragma unroll
    for (int r8 = 0; r8 < 8; ++r8) acc[r8] += lr[r8] * wv;
  }
  #pragma unroll
  for (int r8 = 0; r8 < 8; ++r8)
    out[(size_t)(i0 + rg * 8 + r8) * DIM + j] = fmaxf(acc[r8], 0.f);
}

// ---------------------------------------------------------------------------
extern "C" void kernel_launch(void* const* d_in, const int* in_sizes, int n_in,
                              void* d_out, int out_size, void* d_ws,
                              size_t ws_size, hipStream_t stream) {
  const float* feat  = (const float*)d_in[0];  // [65536][128] f32
  const int*   s2src = (const int*)d_in[1];    // [32768]
  const int*   s2dst = (const int*)d_in[2];    // [8192]
  const float* dif   = (const float*)d_in[3];  // [8192][32768] f32
  const float* w     = (const float*)d_in[4];  // [256][128] f32
  float* out = (float*)d_out;                  // [8192][128] f32

  // ws layout: wsB bf16 [128][32768] = 8 MiB, then partials f32 = 32 MiB
  short* wsB = (short*)d_ws;
  float* wsP = (float*)((char*)d_ws + (size_t)DIM * KTOT * 2);

  prep_kernel<<<KTOT / 64, 256, 0, stream>>>(feat, s2src, wsB);
  gemm_kernel<<<(MTOT / BM) * SPLIT, 256, 0, stream>>>(dif, wsB, wsP);
  finish_kernel<<<MTOT / 16, 256, 0, stream>>>(feat, s2dst, wsP, w, out);
}